// Round 6
// baseline (104.463 us; speedup 1.0000x reference)
//
#include <hip/hip_runtime.h>
#include <math.h>

#define NANCH 16128      // 64*64*3 + 32*32*3 + 16*16*3
#define NSEG  84         // decode segments per image
#define SEGA  192        // anchors per segment
#define NB    16
#define NDET  100
#define SCORE_TH 0.25f
#define IOU_TH   0.5f
#define IMGSZ    512.0f

#define DEC_THREADS 256
#define DEC_DW4     (SEGA * 85 / 4)   // 4080 float4 = 63.75 KB LDS

#define NMS_THREADS 512
#define KCAP   2048
#define NHIST  512
#define SEL_TARGET 256u
#define FASTCAP 512

__device__ __constant__ float c_anchors[18] = {
    12.f,16.f, 19.f,36.f, 40.f,28.f,
    36.f,75.f, 76.f,55.f, 72.f,146.f,
    142.f,110.f, 192.f,243.f, 459.f,401.f
};

__device__ __forceinline__ float sigmoidf_(float x) {
    return 1.0f / (1.0f + expf(-x));
}

// Exact DIoU suppression test; roles: (B*) = accepted box, (c*) = candidate.
// Float expression order identical to the validated round-1..5 kernels (absmax 0).
__device__ __forceinline__ bool suppresses(float Bx, float By, float Bw, float Bh,
                                           float cx, float cy, float cw, float ch) {
    float b1minx = Bx - Bw * 0.5f, b1maxx = Bx + Bw * 0.5f;
    float b1miny = By - Bh * 0.5f, b1maxy = By + Bh * 0.5f;
    float b2minx = cx - cw * 0.5f, b2maxx = cx + cw * 0.5f;
    float b2miny = cy - ch * 0.5f, b2maxy = cy + ch * 0.5f;
    float iw = fmaxf(fminf(b1maxx, b2maxx) - fmaxf(b1minx, b2minx), 0.f);
    float ih = fmaxf(fminf(b1maxy, b2maxy) - fmaxf(b1miny, b2miny), 0.f);
    float inter = iw * ih;
    float uni   = Bw * Bh + cw * ch - inter;
    float iou   = inter / (uni + 1e-9f);
    float ex = fmaxf(b1maxx, b2maxx) - fminf(b1minx, b2minx);
    float ey = fmaxf(b1maxy, b2maxy) - fminf(b1miny, b2miny);
    float c2 = ex * ex + ey * ey + 1e-9f;
    float dx = Bx - cx, dy = By - cy;
    float diou = iou - (dx * dx + dy * dy) / c2;
    return diou > IOU_TH;
}

// key layout: [score_bits:32][16383-idx:14][class:7][0:11]
// u64 ascending order == (score asc, idx desc) -> max = (max score, min idx).

__global__ __launch_bounds__(DEC_THREADS)
void decode_kernel(const float* __restrict__ p0,
                   const float* __restrict__ p1,
                   const float* __restrict__ p2,
                   float4* __restrict__ boxes,
                   unsigned long long* __restrict__ keylist,
                   int* __restrict__ gcount) {
    __shared__ float4 lds4[DEC_DW4];
    __shared__ int wcnt[4];
    __shared__ int gbase;

    int blk = blockIdx.x;
    int b   = blk / NSEG;
    int seg = blk - b * NSEG;

    const float* src; int S, lgS, scale, loc;
    float stride;
    if (seg < 64)      { scale = 0; S = 64; lgS = 6; stride = 8.f;  src = p0; loc = seg * SEGA; }
    else if (seg < 80) { scale = 1; S = 32; lgS = 5; stride = 16.f; src = p1; loc = seg * SEGA - 12288; }
    else               { scale = 2; S = 16; lgS = 4; stride = 32.f; src = p2; loc = seg * SEGA - 15360; }

    // coalesced float4 staging (base multiple of 16320 floats -> 16B aligned)
    const float4* s4 = (const float4*)(src + ((size_t)b * (S * S * 3) + loc) * 85);
    {
        int j = threadIdx.x;
        #pragma unroll
        for (int r = 0; r < 15; ++r, j += DEC_THREADS) lds4[j] = s4[j];
        if (j < DEC_DW4) lds4[j] = s4[j];
    }
    __syncthreads();

    int t = threadIdx.x;
    bool cand = false;
    unsigned long long key = 0ull;
    if (t < SEGA) {
        const float* p = (const float*)lds4 + t * 85;   // stride 85 (odd) -> conflict-free
        int local = loc + t;
        int a    = local % 3;
        int cell = local / 3;
        int gj   = cell & (S - 1);
        int gi   = cell >> lgS;

        float tx = p[0], ty = p[1], tw = p[2], th = p[3], tobj = p[4];

        float bestl = p[5];
        int   bc    = 0;
        #pragma unroll 8
        for (int c = 1; c < 80; ++c) {
            float v = p[5 + c];
            if (v > bestl) { bestl = v; bc = c; }
        }

        float bx = ((sigmoidf_(tx) * 2.0f - 0.5f) + (float)gj) * stride;
        float by = ((sigmoidf_(ty) * 2.0f - 0.5f) + (float)gi) * stride;
        float sw = sigmoidf_(tw) * 2.0f; sw = sw * sw;
        float sh = sigmoidf_(th) * 2.0f; sh = sh * sh;
        float aw = c_anchors[scale * 6 + a * 2];
        float ah = c_anchors[scale * 6 + a * 2 + 1];
        float bw = sw * aw;
        float bh = sh * ah;

        bx = fminf(fmaxf(bx, 0.f), IMGSZ);
        by = fminf(fmaxf(by, 0.f), IMGSZ);
        bw = fminf(fmaxf(bw, 0.f), IMGSZ);
        bh = fminf(fmaxf(bh, 0.f), IMGSZ);

        float score = sigmoidf_(tobj) * sigmoidf_(bestl);
        if (score >= SCORE_TH) {
            cand = true;
            int gidx = seg * SEGA + t;
            boxes[(size_t)b * NANCH + gidx] = make_float4(bx, by, bw, bh);
            key = ((unsigned long long)__float_as_uint(score) << 32)
                | ((unsigned long long)(16383 - gidx) << 18)
                | ((unsigned long long)bc << 11);
        }
    }

    // dense compaction: block claims a contiguous span of the image's keylist
    unsigned long long m = __ballot(cand);
    int lane = t & 63, w = t >> 6;
    if (lane == 0) wcnt[w] = __popcll(m);
    __syncthreads();
    if (t == 0) gbase = atomicAdd(&gcount[b], wcnt[0] + wcnt[1] + wcnt[2] + wcnt[3]);
    __syncthreads();
    if (cand) {
        int basep = gbase;
        #pragma unroll
        for (int j = 0; j < 4; ++j) if (j < w) basep += wcnt[j];
        int pos = basep + (int)__popcll(m & ((1ull << lane) - 1ull));
        keylist[(size_t)b * NANCH + pos] = key;
    }
}

// One block (512 thr) per image: hist -> threshold -> compact -> hybrid sort -> ordered scan.
__global__ __launch_bounds__(NMS_THREADS)
void nms_kernel(const float4* __restrict__ boxes,
                const unsigned long long* __restrict__ keylist,
                const int* __restrict__ gcount,
                float* __restrict__ out) {
    int b    = blockIdx.x;
    int tid  = threadIdx.x;
    int lane = tid & 63;
    int wave = tid >> 6;

    const float4* bb = boxes + (size_t)b * NANCH;
    const unsigned long long* kl = keylist + (size_t)b * NANCH;
    float* o = out + (size_t)b * NDET * 6;

    __shared__ unsigned int       hist8[8][NHIST + 1];   // per-wave copies, padded stride
    __shared__ unsigned long long keyb[KCAP];
    __shared__ float4             acc[NDET];
    __shared__ float              dets[NDET * 6];
    __shared__ int                ctrl[2];   // 0: nsel counter, 1: A accepted
    __shared__ int                sn;

    for (int i = tid; i < 8 * (NHIST + 1); i += NMS_THREADS)
        ((unsigned int*)hist8)[i] = 0u;
    if (tid < 2) ctrl[tid] = 0;
    if (tid == 0) sn = gcount[b];
    __syncthreads();

    int n = sn;

    // ---- private-per-wave histogram over the dense key array ----
    for (int i = tid; i < n; i += NMS_THREADS) {
        int bu = (int)(kl[i] >> 47) - 32000;
        bu = min(bu, NHIST - 1);
        atomicAdd(&hist8[wave][bu], 1u);
    }
    __syncthreads();
    // merge 8 copies into row 0 (1 bucket per thread, conflict-free reads)
    {
        unsigned int s = 0;
        #pragma unroll
        for (int w2 = 0; w2 < 8; ++w2) s += hist8[w2][tid];
        hist8[0][tid] = s;
    }
    __syncthreads();

    int b_hi = NHIST;
    for (int round = 0; round < 64; ++round) {
        // ---- threshold select, computed redundantly by every wave ----
        int b0 = lane * 8;
        unsigned int segsum = 0;
        #pragma unroll
        for (int j = 0; j < 8; ++j) { int bu = b0 + j; if (bu < b_hi) segsum += hist8[0][bu]; }
        unsigned int suf = segsum;                  // inclusive suffix over lanes >= l
        #pragma unroll
        for (int off = 1; off < 64; off <<= 1) {
            unsigned int ov = __shfl_down(suf, off);
            if (lane + off < 64) suf += ov;
        }
        unsigned int remaining = __shfl(suf, 0);
        int A0 = ctrl[1];
        if (remaining == 0u || A0 >= NDET) break;   // uniform exit

        int bstar;
        if (remaining <= (unsigned)FASTCAP) bstar = 0;
        else {
            unsigned int above = (lane == 63) ? 0u : __shfl_down(suf, 1);
            unsigned int run = above;
            int loc = -1; unsigned int locS = 0, locAb = 0;
            #pragma unroll
            for (int j = 7; j >= 0; --j) {
                int bu = b0 + j;
                if (bu < b_hi) {
                    unsigned int prev = run;
                    run += hist8[0][bu];
                    if (loc < 0 && run >= SEL_TARGET) { loc = bu; locS = run; locAb = prev; }
                }
            }
            unsigned long long pk = (loc < 0) ? 0ull
                : (((unsigned long long)(loc + 1) << 32)
                   | ((unsigned long long)locAb << 1)
                   | (unsigned long long)(locS > (unsigned)FASTCAP ? 1u : 0u));
            #pragma unroll
            for (int off = 32; off; off >>= 1) {
                unsigned long long op = __shfl_xor(pk, off);
                if (op > pk) pk = op;
            }
            int loc2 = (int)(pk >> 32) - 1;
            bool fat = (pk & 1ull) != 0ull;
            unsigned int above2 = (unsigned int)((pk >> 1) & 0x7FFFFFFFull);
            // fat bucket: defer it to the continuation unless it's the top of range
            bstar = (fat && above2 > 0u) ? loc2 + 1 : loc2;
        }
        if (tid == 0) ctrl[0] = 0;
        __syncthreads();   // protects ctrl[0] reset + keyb reuse

        // ---- compact keys with bucket in [bstar, b_hi): flat, wave-aggregated ----
        for (int i0 = 0; i0 < n; i0 += NMS_THREADS) {
            int i = i0 + tid;
            unsigned long long key = 0ull;
            bool pass = false;
            if (i < n) {
                key = kl[i];
                int bu = (int)(key >> 47) - 32000;
                bu = min(bu, NHIST - 1);
                pass = (bu >= bstar && bu < b_hi);
            }
            unsigned long long m = __ballot(pass);
            if (m) {
                int basep;
                if (lane == 0) basep = atomicAdd(&ctrl[0], (int)__popcll(m));
                basep = __shfl(basep, 0);
                if (pass) {
                    int pos = basep + (int)__popcll(m & ((1ull << lane) - 1ull));
                    if (pos < KCAP) keyb[pos] = key;
                }
            }
        }
        __syncthreads();

        int nsel = ctrl[0]; if (nsel > KCAP) nsel = KCAP;
        int N = 64; while (N < nsel) N <<= 1;

        if (nsel > 0) {
            if (nsel <= FASTCAP) {
                // ---- hybrid bitonic: 1 elem/thread, shfl for j2<64 ----
                unsigned long long v = (tid < nsel) ? keyb[tid] : 0ull;
                for (int k2 = 2; k2 <= N; k2 <<= 1) {
                    for (int j2 = k2 >> 1; j2 > 0; j2 >>= 1) {
                        unsigned long long pv;
                        if (j2 < 64) {
                            pv = __shfl_xor(v, j2);
                        } else {
                            __syncthreads();
                            keyb[tid] = v;
                            __syncthreads();
                            pv = keyb[tid ^ j2];
                        }
                        bool dir     = ((tid & k2) == 0);
                        bool keepmin = (((tid & j2) == 0) == dir);
                        bool take    = keepmin ? (pv < v) : (pv > v);
                        if (take) v = pv;
                    }
                }
                __syncthreads();
                keyb[tid] = v;
                __syncthreads();
            } else {
                // ---- general LDS bitonic fallback (rare: fat-bucket case) ----
                for (int t2 = tid; t2 < N; t2 += NMS_THREADS)
                    if (t2 >= nsel) keyb[t2] = 0ull;
                for (int k2 = 2; k2 <= N; k2 <<= 1) {
                    for (int j2 = k2 >> 1; j2 > 0; j2 >>= 1) {
                        __syncthreads();
                        for (int t2 = tid; t2 < N; t2 += NMS_THREADS) {
                            int p2 = t2 ^ j2;
                            if (p2 > t2) {
                                unsigned long long av = keyb[t2], bv = keyb[p2];
                                bool up = ((t2 & k2) == 0);
                                if (up ? (av > bv) : (av < bv)) { keyb[t2] = bv; keyb[p2] = av; }
                            }
                        }
                    }
                }
                __syncthreads();
            }

            // ---- ordered greedy scan (wave 0), next-chunk prefetched ----
            if (wave == 0) {
                int A = ctrl[1];
                int cb = N - 1;
                int pos = cb - lane;
                unsigned long long key = (pos >= 0) ? keyb[pos] : 0ull;
                float4 c = make_float4(0.f, 0.f, 0.f, 0.f);
                {
                    int idx = 16383 - (int)((key >> 18) & 0x3FFFull);
                    if (key != 0ull) c = bb[idx];
                }
                while (A < NDET) {
                    // prefetch next chunk (keyb is LDS; box load hides behind scan)
                    int ncb = cb - 64;
                    unsigned long long nkey = 0ull;
                    float4 nc = make_float4(0.f, 0.f, 0.f, 0.f);
                    if (ncb >= 0) {
                        int npos = ncb - lane;
                        nkey = (npos >= 0) ? keyb[npos] : 0ull;
                        int nidx = 16383 - (int)((nkey >> 18) & 0x3FFFull);
                        if (nkey != 0ull) nc = bb[nidx];
                    }

                    bool valid = (key != 0ull);
                    if (__ballot(valid) == 0ull) break;   // zeros pad the bottom
                    float scv = __uint_as_float((unsigned int)(key >> 32));
                    float cls = (float)((key >> 11) & 0x7Full);

                    bool alive = valid;
                    for (int i = 0; i < A; ++i) {          // pre-check vs accepted
                        float4 a = acc[i];
                        if (alive && suppresses(a.x, a.y, a.z, a.w, c.x, c.y, c.z, c.w))
                            alive = false;
                    }
                    unsigned long long mm = __ballot(alive);
                    while (mm && A < NDET) {
                        int l = (int)__builtin_ctzll(mm);  // highest-key survivor
                        float Bx = __shfl(c.x, l), By = __shfl(c.y, l);
                        float Bw = __shfl(c.z, l), Bh = __shfl(c.w, l);
                        if (lane == l) {
                            acc[A] = c;
                            dets[A * 6 + 0] = c.x;
                            dets[A * 6 + 1] = c.y;
                            dets[A * 6 + 2] = c.z;
                            dets[A * 6 + 3] = c.w;
                            dets[A * 6 + 4] = scv;
                            dets[A * 6 + 5] = cls;
                            alive = false;
                        }
                        A++;
                        if (alive && lane > l &&
                            suppresses(Bx, By, Bw, Bh, c.x, c.y, c.z, c.w))
                            alive = false;
                        mm = __ballot(alive);
                    }
                    if (ncb < 0) break;
                    cb = ncb; key = nkey; c = nc;
                }
                if (lane == 0) ctrl[1] = A;
            }
        }
        __syncthreads();
        if (bstar >= b_hi) break;    // safety (unreachable by construction)
        b_hi = bstar;
    }

    __syncthreads();
    int A = ctrl[1];
    for (int i = tid; i < NDET * 6; i += NMS_THREADS)
        if (i >= A * 6) dets[i] = 0.0f;
    __syncthreads();
    for (int i = tid; i < NDET * 6; i += NMS_THREADS) o[i] = dets[i];
}

extern "C" void kernel_launch(void* const* d_in, const int* in_sizes, int n_in,
                              void* d_out, int out_size, void* d_ws, size_t ws_size,
                              hipStream_t stream) {
    const float* p0 = (const float*)d_in[0];
    const float* p1 = (const float*)d_in[1];
    const float* p2 = (const float*)d_in[2];
    float* out = (float*)d_out;

    char* ws = (char*)d_ws;
    float4*             boxes   = (float4*)ws;                                   // 4,128,768 B
    unsigned long long* keylist = (unsigned long long*)(ws + (size_t)NB * NANCH * sizeof(float4));
    int*                gcount  = (int*)(ws + (size_t)NB * NANCH * (sizeof(float4) + sizeof(unsigned long long)));

    hipMemsetAsync(gcount, 0, NB * sizeof(int), stream);
    decode_kernel<<<NB * NSEG, DEC_THREADS, 0, stream>>>(p0, p1, p2, boxes, keylist, gcount);
    nms_kernel<<<NB, NMS_THREADS, 0, stream>>>(boxes, keylist, gcount, out);
}